// Round 1
// baseline (774.298 us; speedup 1.0000x reference)
//
#include <hip/hip_runtime.h>

// ============================================================================
// VectorChannel: restructured.
//   logits[e] = PA[col] + PB[row]  (per-node precompute kills the E-sized GEMM)
//   rotation:  R_rel@vj = Ri^T @ (Rj@vj) -> precompute g[n] = R_n @ v_n
//   P stored column-permuted: P[n][c*32+kk] (c = k%16, kk = k/16) so each
//   16-lane group's lane c reads its weight column contiguously.
// ============================================================================

#define DD 128
#define VV 16
#define TV 48      // 3*V
#define NK 512     // 2*V*V

__device__ __forceinline__ float waveRedSum64(float v){
    #pragma unroll
    for (int off = 32; off > 0; off >>= 1) v += __shfl_xor(v, off, 64);
    return v;
}
__device__ __forceinline__ float groupRedSum16(float v){
    #pragma unroll
    for (int off = 1; off < 16; off <<= 1) v += __shfl_xor(v, off, 64);
    return v;
}
__device__ __forceinline__ float sigmoidf_(float y){
    return 1.0f / (1.0f + __expf(-y));
}

// --- detect whether edge_index is int64 (all high dwords zero) ---------------
__global__ void detect_i64(const int* p, int nchk, int* flag){
    __shared__ int s;
    if (threadIdx.x == 0) s = 0;
    __syncthreads();
    int nz = 0;
    for (int i = threadIdx.x; i < nchk; i += blockDim.x) nz |= (p[2*i+1] != 0);
    if (nz) atomicOr(&s, 1);
    __syncthreads();
    if (threadIdx.x == 0) *flag = s ? 0 : 1;   // 1 => int64
}

__global__ void cvt_idx(const void* src, int* dst, int n, const int* flag){
    int i = blockIdx.x*blockDim.x + threadIdx.x;
    if (i >= n) return;
    if (*flag) dst[i] = (int)((const long long*)src)[i];
    else       dst[i] = ((const int*)src)[i];
}

// --- build transposed+permuted weight matrix for the P GEMM ------------------
// Wt[d][j], j<512: PA cols (c=j/32,kk=j%32 -> k=kk*16+c, Wi[k][d], bias bi[k])
//           j>=512: PB cols (Wi[k][128+d], bias 0)
__global__ void build_wt(const float* __restrict__ Wi, const float* __restrict__ bi,
                         const float* __restrict__ gi, const float* __restrict__ bbi,
                         float* __restrict__ Wt, float* __restrict__ bias_t,
                         float* __restrict__ gi_t, float* __restrict__ bbi_t){
    int j = blockIdx.x;        // 0..1023
    int d = threadIdx.x;       // 0..127
    int half = j >> 9;
    int jj = j & 511;
    int c = jj >> 5, kk = jj & 31;
    int k = kk*16 + c;
    Wt[d*1024 + j] = Wi[k*256 + half*128 + d];
    if (d == 0){
        bias_t[j] = half ? 0.0f : bi[k];
        if (!half){ gi_t[jj] = gi[k]; bbi_t[jj] = bbi[k]; }
    }
}

// --- vector_init: 2x (Linear+LN+SiLU), one wave per node; also emit g=R@v ----
__global__ __launch_bounds__(256) void vinit(
        const float* __restrict__ h,
        const float* __restrict__ W1, const float* __restrict__ b1,
        const float* __restrict__ g1, const float* __restrict__ bb1,
        const float* __restrict__ W2, const float* __restrict__ b2,
        const float* __restrict__ g2, const float* __restrict__ bb2,
        const float* __restrict__ frames,
        float* __restrict__ vecs, float* __restrict__ gvec, int N){
    __shared__ float hs[4][DD];
    __shared__ float ts[4][TV];
    int w = threadIdx.x >> 6, l = threadIdx.x & 63;
    int n = blockIdx.x*4 + w;
    int nr = n < N ? n : N-1;
    hs[w][l]      = h[(size_t)nr*DD + l];
    hs[w][l + 64] = h[(size_t)nr*DD + 64 + l];
    __syncthreads();

    float o1 = 0.0f;
    if (l < TV){
        o1 = b1[l];
        const float* wr = W1 + l*DD;
        #pragma unroll
        for (int d = 0; d < DD; d += 4){
            float4 w4 = *(const float4*)(wr + d);
            o1 += hs[w][d]*w4.x + hs[w][d+1]*w4.y + hs[w][d+2]*w4.z + hs[w][d+3]*w4.w;
        }
    }
    float s  = waveRedSum64(l < TV ? o1 : 0.0f);
    float mu = s * (1.0f/TV);
    float dv = l < TV ? (o1 - mu) : 0.0f;
    float sq = waveRedSum64(dv*dv);
    float inv = rsqrtf(sq*(1.0f/TV) + 1e-5f);
    if (l < TV){
        float y = g1[l]*(dv*inv) + bb1[l];
        ts[w][l] = y * sigmoidf_(y);
    }
    __syncthreads();

    float o2 = 0.0f;
    if (l < TV){
        o2 = b2[l];
        const float* wr = W2 + l*TV;
        #pragma unroll
        for (int j = 0; j < TV; j += 4){
            float4 w4 = *(const float4*)(wr + j);
            o2 += ts[w][j]*w4.x + ts[w][j+1]*w4.y + ts[w][j+2]*w4.z + ts[w][j+3]*w4.w;
        }
    }
    s  = waveRedSum64(l < TV ? o2 : 0.0f);
    mu = s * (1.0f/TV);
    dv = l < TV ? (o2 - mu) : 0.0f;
    sq = waveRedSum64(dv*dv);
    inv = rsqrtf(sq*(1.0f/TV) + 1e-5f);
    __syncthreads();   // ts reuse below
    if (l < TV){
        float y = g2[l]*(dv*inv) + bb2[l];
        float t2 = y * sigmoidf_(y);
        if (n < N) vecs[(size_t)n*TV + l] = t2;
        ts[w][l] = t2;
    }
    __syncthreads();
    if (l < TV && n < N){
        int cc = l/3, oo = l%3;  // g[n][cc][oo] = sum_j R[oo][j]*v[cc][j]
        const float* R = frames + (size_t)n*9;
        float gv = R[oo*3+0]*ts[w][cc*3+0] + R[oo*3+1]*ts[w][cc*3+1] + R[oo*3+2]*ts[w][cc*3+2];
        gvec[(size_t)n*TV + l] = gv;
    }
}

// --- P = h @ Wt + bias_t : [N x 128] @ [128 x 1024] --------------------------
#define BM 64
#define BN 128
#define BK 32
__global__ __launch_bounds__(256) void gemm_p(
        const float* __restrict__ h, const float* __restrict__ Wt,
        const float* __restrict__ bias_t, float* __restrict__ P, int N){
    __shared__ float As[BK][BM];
    __shared__ float Bs[BK][BN + 4];
    int tid = threadIdx.x;
    int n0 = blockIdx.x * BN;
    int m0 = blockIdx.y * BM;
    int tm = tid >> 4, tn = tid & 15;
    float acc[4][8];
    #pragma unroll
    for (int i = 0; i < 4; i++)
        #pragma unroll
        for (int j = 0; j < 8; j++) acc[i][j] = 0.0f;

    int lm  = tid >> 2;          // 0..63 node in tile
    int lc4 = tid & 3;           // k-chunk of 8
    int grow = m0 + lm; if (grow > N-1) grow = N-1;
    const float* hp = h + (size_t)grow*DD + lc4*8;
    int bkb = tid >> 5;          // 0..7
    int bjj = tid & 31;          // col group of 4

    for (int kt = 0; kt < DD; kt += BK){
        float4 a0 = *(const float4*)(hp + kt);
        float4 a1 = *(const float4*)(hp + kt + 4);
        As[lc4*8+0][lm] = a0.x; As[lc4*8+1][lm] = a0.y;
        As[lc4*8+2][lm] = a0.z; As[lc4*8+3][lm] = a0.w;
        As[lc4*8+4][lm] = a1.x; As[lc4*8+5][lm] = a1.y;
        As[lc4*8+6][lm] = a1.z; As[lc4*8+7][lm] = a1.w;
        #pragma unroll
        for (int r = 0; r < 4; r++){
            float4 b4 = *(const float4*)(Wt + (size_t)(kt + bkb*4 + r)*1024 + n0 + bjj*4);
            *(float4*)&Bs[bkb*4+r][bjj*4] = b4;
        }
        __syncthreads();
        #pragma unroll
        for (int k = 0; k < BK; k++){
            float4 a   = *(const float4*)&As[k][tm*4];
            float4 blo = *(const float4*)&Bs[k][tn*4];
            float4 bhi = *(const float4*)&Bs[k][64 + tn*4];
            float am[4] = {a.x, a.y, a.z, a.w};
            float bv[8] = {blo.x, blo.y, blo.z, blo.w, bhi.x, bhi.y, bhi.z, bhi.w};
            #pragma unroll
            for (int mi = 0; mi < 4; mi++)
                #pragma unroll
                for (int ni = 0; ni < 8; ni++)
                    acc[mi][ni] = fmaf(am[mi], bv[ni], acc[mi][ni]);
        }
        __syncthreads();
    }
    #pragma unroll
    for (int mi = 0; mi < 4; mi++){
        size_t rowm = (size_t)(m0 + tm*4 + mi);       // padded rows exist
        float4 olo, ohi;
        olo.x = acc[mi][0] + bias_t[n0 + tn*4 + 0];
        olo.y = acc[mi][1] + bias_t[n0 + tn*4 + 1];
        olo.z = acc[mi][2] + bias_t[n0 + tn*4 + 2];
        olo.w = acc[mi][3] + bias_t[n0 + tn*4 + 3];
        ohi.x = acc[mi][4] + bias_t[n0 + 64 + tn*4 + 0];
        ohi.y = acc[mi][5] + bias_t[n0 + 64 + tn*4 + 1];
        ohi.z = acc[mi][6] + bias_t[n0 + 64 + tn*4 + 2];
        ohi.w = acc[mi][7] + bias_t[n0 + 64 + tn*4 + 3];
        *(float4*)(P + rowm*1024 + n0 + tn*4)      = olo;
        *(float4*)(P + rowm*1024 + n0 + 64 + tn*4) = ohi;
    }
}

// --- out = v_prev ------------------------------------------------------------
__global__ void copy_vprev(const float* __restrict__ vp, float* __restrict__ out, int n){
    int i = blockIdx.x*blockDim.x + threadIdx.x;
    if (i < n) out[i] = vp[i];
}

// --- edge kernel: 16 lanes per edge, 16 edges per 256-block ------------------
__global__ __launch_bounds__(256) void edge_k(
        const float* __restrict__ P, const float* __restrict__ vecs,
        const float* __restrict__ gvec, const float* __restrict__ frames,
        const int* __restrict__ idx, const float* __restrict__ gi_t,
        const float* __restrict__ bbi_t, float* __restrict__ out, int E){
    __shared__ float svs[16][100];      // [group][2V*3] padded to avoid bank alias
    int g = threadIdx.x >> 4, c = threadIdx.x & 15;
    int e = blockIdx.x*16 + g;
    bool active = e < E;
    int ec = active ? e : 0;
    int row = idx[ec], col = idx[E + ec];

    const float4* pa = (const float4*)(P + (size_t)col*1024 + c*32);
    const float4* pb = (const float4*)(P + (size_t)row*1024 + 512 + c*32);
    float l[32];
    #pragma unroll
    for (int q = 0; q < 8; q++){
        float4 a = pa[q], b = pb[q];
        l[4*q+0] = a.x + b.x; l[4*q+1] = a.y + b.y;
        l[4*q+2] = a.z + b.z; l[4*q+3] = a.w + b.w;
    }
    float s = 0.0f;
    #pragma unroll
    for (int i = 0; i < 32; i++) s += l[i];
    s = groupRedSum16(s);
    float mu = s * (1.0f/NK);
    float sq = 0.0f;
    #pragma unroll
    for (int i = 0; i < 32; i++){ float d = l[i] - mu; l[i] = d; sq = fmaf(d, d, sq); }
    sq = groupRedSum16(sq);
    float inv = rsqrtf(sq*(1.0f/NK) + 1e-5f);

    const float4* g4 = (const float4*)(gi_t  + c*32);
    const float4* b4 = (const float4*)(bbi_t + c*32);
    float w[32];
    #pragma unroll
    for (int q = 0; q < 8; q++){
        float4 gg = g4[q], bv = b4[q];
        float gx[4] = {gg.x, gg.y, gg.z, gg.w};
        float bx[4] = {bv.x, bv.y, bv.z, bv.w};
        #pragma unroll
        for (int r = 0; r < 4; r++){
            float y = fmaf(gx[r], l[4*q+r]*inv, bx[r]);
            w[4*q+r] = sigmoidf_(y);
        }
    }

    // sv: [kk<16] = vecs[col][kk], [16+c] = Ri^T @ gvec[row][c]
    {
        const float* vc = vecs + (size_t)col*TV + c*3;
        svs[g][c*3+0] = vc[0]; svs[g][c*3+1] = vc[1]; svs[g][c*3+2] = vc[2];
        const float* gr = gvec + (size_t)row*TV + c*3;
        float gm0 = gr[0], gm1 = gr[1], gm2 = gr[2];
        const float* R = frames + (size_t)col*9;
        #pragma unroll
        for (int i = 0; i < 3; i++)
            svs[g][(16+c)*3+i] = R[0*3+i]*gm0 + R[1*3+i]*gm1 + R[2*3+i]*gm2;
    }
    __syncthreads();

    float acc0 = 0.0f, acc1 = 0.0f, acc2 = 0.0f;
    const float4* sv4 = (const float4*)&svs[g][0];
    #pragma unroll
    for (int q = 0; q < 24; q++){
        float4 x = sv4[q];
        float xr[4] = {x.x, x.y, x.z, x.w};
        #pragma unroll
        for (int r = 0; r < 4; r++){
            const int t  = 4*q + r;     // flat (kk,o)
            const int kk = t / 3;
            const int o  = t % 3;
            float p = xr[r] * w[kk];
            if (o == 0) acc0 += p;
            else if (o == 1) acc1 += p;
            else acc2 += p;
        }
    }
    if (active){
        float* op = out + (size_t)col*TV + c*3;
        atomicAdd(op + 0, acc0);
        atomicAdd(op + 1, acc1);
        atomicAdd(op + 2, acc2);
    }
}

// ============================================================================
extern "C" void kernel_launch(void* const* d_in, const int* in_sizes, int n_in,
                              void* d_out, int out_size, void* d_ws, size_t ws_size,
                              hipStream_t stream){
    const float* h      = (const float*)d_in[1];
    const void*  eidx   = d_in[2];
    const float* frames = (const float*)d_in[3];
    const float* vprev  = (const float*)d_in[5];
    const float* W1  = (const float*)d_in[6];
    const float* b1  = (const float*)d_in[7];
    const float* g1  = (const float*)d_in[8];
    const float* bb1 = (const float*)d_in[9];
    const float* W2  = (const float*)d_in[10];
    const float* b2  = (const float*)d_in[11];
    const float* g2  = (const float*)d_in[12];
    const float* bb2 = (const float*)d_in[13];
    const float* Wi  = (const float*)d_in[14];
    const float* bi  = (const float*)d_in[15];
    const float* gi  = (const float*)d_in[16];
    const float* bbi = (const float*)d_in[17];
    float* out = (float*)d_out;

    const int N = in_sizes[1] / DD;
    const int E = in_sizes[2] / 2;
    const int Np = ((N + BM - 1) / BM) * BM;

    // workspace carve-up (floats)
    float* ws     = (float*)d_ws;
    float* Wt     = ws;                       // 128*1024
    float* bias_t = Wt + 128*1024;            // 1024
    float* gi_t   = bias_t + 1024;            // 512
    float* bbi_t  = gi_t + 512;               // 512
    float* vecs   = bbi_t + 512;              // N*48
    float* gvec   = vecs + (size_t)N*TV;      // N*48
    int*   idx32  = (int*)(gvec + (size_t)N*TV);  // 2E
    int*   dflag  = idx32 + 2*(size_t)E;      // 1 (+3 pad)
    size_t ofs    = (size_t)(dflag + 4 - (int*)d_ws); // ints consumed
    ofs = (ofs + 3) & ~(size_t)3;             // align to 16B in floats
    float* P      = (float*)d_ws + ofs;       // Np*1024

    detect_i64<<<1, 256, 0, stream>>>((const int*)eidx, 4096, dflag);
    cvt_idx<<<(2*E + 255)/256, 256, 0, stream>>>(eidx, idx32, 2*E, dflag);
    build_wt<<<1024, 128, 0, stream>>>(Wi, bi, gi, bbi, Wt, bias_t, gi_t, bbi_t);
    vinit<<<(N + 3)/4, 256, 0, stream>>>(h, W1, b1, g1, bb1, W2, b2, g2, bb2,
                                         frames, vecs, gvec, N);
    dim3 ggrid(1024/BN, (N + BM - 1)/BM);
    gemm_p<<<ggrid, 256, 0, stream>>>(h, Wt, bias_t, P, N);
    copy_vprev<<<(N*TV + 255)/256, 256, 0, stream>>>(vprev, out, N*TV);
    edge_k<<<(E + 15)/16, 256, 0, stream>>>(P, vecs, gvec, frames, idx32,
                                            gi_t, bbi_t, out, E);
    (void)Np; (void)ws_size; (void)n_in; (void)out_size;
}

// Round 3
// 590.783 us; speedup vs baseline: 1.3106x; 1.3106x over previous
//
#include <hip/hip_runtime.h>

// ============================================================================
// VectorChannel, round 2 (re-land after broker timeout): CSR + bf16 P.
//   logits[e] = PA[col] + PB[row]   (per-node GEMM, 16x smaller than E-GEMM)
//   rotation:  R_rel@vj = Ri^T @ (Rj@vj), g[n] = R_n@v_n precomputed
//   P column-permuted: P[n][c*32+kk] <-> original k = kk*16+c, stored bf16.
//   Edges grouped by col (CSR) -> PA read once/node, no output atomics.
// ============================================================================

#define DD 128
#define VV 16
#define TV 48      // 3*V
#define NK 512     // 2*V*V

__device__ __forceinline__ float bf2f_hi(unsigned u){  // high half already in place
    union{unsigned u; float f;} v; v.u = u & 0xffff0000u; return v.f;
}
__device__ __forceinline__ float bf2f_lo(unsigned u){
    union{unsigned u; float f;} v; v.u = u << 16; return v.f;
}
__device__ __forceinline__ unsigned short f2bf(float f){
    union{float f; unsigned u;} v; v.f = f;
    unsigned r = v.u + 0x7fffu + ((v.u >> 16) & 1u);   // RTNE
    return (unsigned short)(r >> 16);
}
__device__ __forceinline__ void unpack8(uint4 q, float* d){
    d[0]=bf2f_lo(q.x); d[1]=bf2f_hi(q.x);
    d[2]=bf2f_lo(q.y); d[3]=bf2f_hi(q.y);
    d[4]=bf2f_lo(q.z); d[5]=bf2f_hi(q.z);
    d[6]=bf2f_lo(q.w); d[7]=bf2f_hi(q.w);
}
__device__ __forceinline__ float waveRedSum64(float v){
    #pragma unroll
    for (int off = 32; off > 0; off >>= 1) v += __shfl_xor(v, off, 64);
    return v;
}

// --- detect whether edge_index is int64 (all high dwords zero) ---------------
__global__ void detect_i64(const int* p, int nchk, int* flag){
    __shared__ int s;
    if (threadIdx.x == 0) s = 0;
    __syncthreads();
    int nz = 0;
    for (int i = threadIdx.x; i < nchk; i += blockDim.x) nz |= (p[2*i+1] != 0);
    if (nz) atomicOr(&s, 1);
    __syncthreads();
    if (threadIdx.x == 0) *flag = s ? 0 : 1;   // 1 => int64
}

__global__ void zero_cnt(int* cnt, int n){
    int i = blockIdx.x*blockDim.x + threadIdx.x;
    if (i < n) cnt[i] = 0;
}

// convert indices to i32 AND histogram the cols
__global__ void cvt_hist(const void* __restrict__ src, int* __restrict__ dst,
                         int* __restrict__ cnt, int n, int E,
                         const int* __restrict__ flag){
    int i = blockIdx.x*blockDim.x + threadIdx.x;
    if (i >= n) return;
    int v = (*flag) ? (int)((const long long*)src)[i] : ((const int*)src)[i];
    dst[i] = v;
    if (i >= E) atomicAdd(&cnt[v], 1);   // i>=E => col array
}

// exclusive scan of cnt[N] -> start[N+1], cursor[N]=start[N(i)]  (1 block)
__global__ __launch_bounds__(1024) void scan_k(const int* __restrict__ cnt,
        int* __restrict__ start, int* __restrict__ cursor, int N){
    __shared__ int wsum[16];
    __shared__ int woff[16];
    __shared__ int btot;
    __shared__ int carry;
    int tid = threadIdx.x;
    int lane = tid & 63, wid = tid >> 6;
    if (tid == 0) carry = 0;
    __syncthreads();
    for (int base = 0; base < N; base += 1024){
        int i = base + tid;
        int x = (i < N) ? cnt[i] : 0;
        int v = x;
        #pragma unroll
        for (int off = 1; off < 64; off <<= 1){
            int t = __shfl_up(v, off, 64);
            if (lane >= off) v += t;
        }
        if (lane == 63) wsum[wid] = v;
        __syncthreads();
        if (wid == 0 && lane < 16){
            int s = wsum[lane];
            int sv = s;
            #pragma unroll
            for (int off = 1; off < 16; off <<= 1){
                int t = __shfl_up(sv, off, 64);
                if (lane >= off) sv += t;
            }
            woff[lane] = sv - s;
            if (lane == 15) btot = sv;
        }
        __syncthreads();
        if (i < N){
            int excl = v - x + woff[wid] + carry;
            start[i] = excl;
            cursor[i] = excl;
        }
        __syncthreads();
        if (tid == 0) carry += btot;
        __syncthreads();
    }
    if (tid == 0) start[N] = carry;
}

__global__ void scatter_k(const int* __restrict__ idx, int* __restrict__ cursor,
                          int* __restrict__ elist, int E){
    int e = blockIdx.x*blockDim.x + threadIdx.x;
    if (e >= E) return;
    int col = idx[E + e], row = idx[e];
    int pos = atomicAdd(&cursor[col], 1);
    elist[pos] = row;
}

// --- build transposed+permuted weight matrix for the P GEMM ------------------
__global__ void build_wt(const float* __restrict__ Wi, const float* __restrict__ bi,
                         const float* __restrict__ gi, const float* __restrict__ bbi,
                         float* __restrict__ Wt, float* __restrict__ bias_t,
                         float* __restrict__ gi_t, float* __restrict__ bbi_t){
    int j = blockIdx.x;        // 0..1023
    int d = threadIdx.x;       // 0..127
    int half = j >> 9;
    int jj = j & 511;
    int c = jj >> 5, kk = jj & 31;
    int k = kk*16 + c;
    Wt[d*1024 + j] = Wi[k*256 + half*128 + d];
    if (d == 0){
        bias_t[j] = half ? 0.0f : bi[k];
        if (!half){ gi_t[jj] = gi[k]; bbi_t[jj] = bbi[k]; }
    }
}

// --- vector_init: 2x (Linear+LN+SiLU), one wave per node; also emit g=R@v ----
__global__ __launch_bounds__(256) void vinit(
        const float* __restrict__ h,
        const float* __restrict__ W1, const float* __restrict__ b1,
        const float* __restrict__ g1, const float* __restrict__ bb1,
        const float* __restrict__ W2, const float* __restrict__ b2,
        const float* __restrict__ g2, const float* __restrict__ bb2,
        const float* __restrict__ frames,
        float* __restrict__ vecs, float* __restrict__ gvec, int N){
    __shared__ float hs[4][DD];
    __shared__ float ts[4][TV];
    int w = threadIdx.x >> 6, l = threadIdx.x & 63;
    int n = blockIdx.x*4 + w;
    int nr = n < N ? n : N-1;
    hs[w][l]      = h[(size_t)nr*DD + l];
    hs[w][l + 64] = h[(size_t)nr*DD + 64 + l];
    __syncthreads();

    float o1 = 0.0f;
    if (l < TV){
        o1 = b1[l];
        const float* wr = W1 + l*DD;
        #pragma unroll
        for (int d = 0; d < DD; d += 4){
            float4 w4 = *(const float4*)(wr + d);
            o1 += hs[w][d]*w4.x + hs[w][d+1]*w4.y + hs[w][d+2]*w4.z + hs[w][d+3]*w4.w;
        }
    }
    float s  = waveRedSum64(l < TV ? o1 : 0.0f);
    float mu = s * (1.0f/TV);
    float dv = l < TV ? (o1 - mu) : 0.0f;
    float sq = waveRedSum64(dv*dv);
    float inv = rsqrtf(sq*(1.0f/TV) + 1e-5f);
    if (l < TV){
        float y = g1[l]*(dv*inv) + bb1[l];
        ts[w][l] = y / (1.0f + __expf(-y));
    }
    __syncthreads();

    float o2 = 0.0f;
    if (l < TV){
        o2 = b2[l];
        const float* wr = W2 + l*TV;
        #pragma unroll
        for (int j = 0; j < TV; j += 4){
            float4 w4 = *(const float4*)(wr + j);
            o2 += ts[w][j]*w4.x + ts[w][j+1]*w4.y + ts[w][j+2]*w4.z + ts[w][j+3]*w4.w;
        }
    }
    s  = waveRedSum64(l < TV ? o2 : 0.0f);
    mu = s * (1.0f/TV);
    dv = l < TV ? (o2 - mu) : 0.0f;
    sq = waveRedSum64(dv*dv);
    inv = rsqrtf(sq*(1.0f/TV) + 1e-5f);
    __syncthreads();
    if (l < TV){
        float y = g2[l]*(dv*inv) + bb2[l];
        float t2 = y / (1.0f + __expf(-y));
        if (n < N) vecs[(size_t)n*TV + l] = t2;
        ts[w][l] = t2;
    }
    __syncthreads();
    if (l < TV && n < N){
        int cc = l/3, oo = l%3;  // g[n][cc][oo] = sum_j R[oo][j]*v[cc][j]
        const float* R = frames + (size_t)n*9;
        float gv = R[oo*3+0]*ts[w][cc*3+0] + R[oo*3+1]*ts[w][cc*3+1] + R[oo*3+2]*ts[w][cc*3+2];
        gvec[(size_t)n*TV + l] = gv;
    }
}

// --- P = h @ Wt + bias_t : [N x 128] @ [128 x 1024], bf16 out ----------------
#define BM 64
#define BN 128
#define BK 32
__global__ __launch_bounds__(256) void gemm_p(
        const float* __restrict__ h, const float* __restrict__ Wt,
        const float* __restrict__ bias_t, unsigned short* __restrict__ P, int N){
    __shared__ float As[BK][BM];
    __shared__ float Bs[BK][BN + 4];
    int tid = threadIdx.x;
    int n0 = blockIdx.x * BN;
    int m0 = blockIdx.y * BM;
    int tm = tid >> 4, tn = tid & 15;
    float acc[4][8];
    #pragma unroll
    for (int i = 0; i < 4; i++)
        #pragma unroll
        for (int j = 0; j < 8; j++) acc[i][j] = 0.0f;

    int lm  = tid >> 2;          // 0..63 node in tile
    int lc4 = tid & 3;           // k-chunk of 8
    int grow = m0 + lm; if (grow > N-1) grow = N-1;
    const float* hp = h + (size_t)grow*DD + lc4*8;
    int bkb = tid >> 5;          // 0..7
    int bjj = tid & 31;          // col group of 4

    for (int kt = 0; kt < DD; kt += BK){
        float4 a0 = *(const float4*)(hp + kt);
        float4 a1 = *(const float4*)(hp + kt + 4);
        As[lc4*8+0][lm] = a0.x; As[lc4*8+1][lm] = a0.y;
        As[lc4*8+2][lm] = a0.z; As[lc4*8+3][lm] = a0.w;
        As[lc4*8+4][lm] = a1.x; As[lc4*8+5][lm] = a1.y;
        As[lc4*8+6][lm] = a1.z; As[lc4*8+7][lm] = a1.w;
        #pragma unroll
        for (int r = 0; r < 4; r++){
            float4 b4 = *(const float4*)(Wt + (size_t)(kt + bkb*4 + r)*1024 + n0 + bjj*4);
            *(float4*)&Bs[bkb*4+r][bjj*4] = b4;
        }
        __syncthreads();
        #pragma unroll
        for (int k = 0; k < BK; k++){
            float4 a   = *(const float4*)&As[k][tm*4];
            float4 blo = *(const float4*)&Bs[k][tn*4];
            float4 bhi = *(const float4*)&Bs[k][64 + tn*4];
            float am[4] = {a.x, a.y, a.z, a.w};
            float bv[8] = {blo.x, blo.y, blo.z, blo.w, bhi.x, bhi.y, bhi.z, bhi.w};
            #pragma unroll
            for (int mi = 0; mi < 4; mi++)
                #pragma unroll
                for (int ni = 0; ni < 8; ni++)
                    acc[mi][ni] = fmaf(am[mi], bv[ni], acc[mi][ni]);
        }
        __syncthreads();
    }
    #pragma unroll
    for (int mi = 0; mi < 4; mi++){
        size_t rowm = (size_t)(m0 + tm*4 + mi);       // padded rows exist
        ushort4 olo, ohi;
        olo.x = f2bf(acc[mi][0] + bias_t[n0 + tn*4 + 0]);
        olo.y = f2bf(acc[mi][1] + bias_t[n0 + tn*4 + 1]);
        olo.z = f2bf(acc[mi][2] + bias_t[n0 + tn*4 + 2]);
        olo.w = f2bf(acc[mi][3] + bias_t[n0 + tn*4 + 3]);
        ohi.x = f2bf(acc[mi][4] + bias_t[n0 + 64 + tn*4 + 0]);
        ohi.y = f2bf(acc[mi][5] + bias_t[n0 + 64 + tn*4 + 1]);
        ohi.z = f2bf(acc[mi][6] + bias_t[n0 + 64 + tn*4 + 2]);
        ohi.w = f2bf(acc[mi][7] + bias_t[n0 + 64 + tn*4 + 3]);
        *(ushort4*)(P + rowm*1024 + n0 + tn*4)      = olo;
        *(ushort4*)(P + rowm*1024 + n0 + 64 + tn*4) = ohi;
    }
}

// --- node kernel: one wave per node, 4 edges in flight (16 lanes each) -------
__global__ __launch_bounds__(256) void node_k(
        const unsigned short* __restrict__ P,
        const float* __restrict__ vecs, const float* __restrict__ gvec,
        const float* __restrict__ frames, const int* __restrict__ start,
        const int* __restrict__ elist, const float* __restrict__ vprev,
        const float* __restrict__ gi_t, const float* __restrict__ bbi_t,
        float* __restrict__ out, int N){
    __shared__ float vi_s[4][TV];
    __shared__ float vj_s[4][4][52];   // stride 52: subs land on banks {0,20,8,28}
    int wv = threadIdx.x >> 6, ln = threadIdx.x & 63;
    int sub = ln >> 4, c = ln & 15;
    int n0 = blockIdx.x*4 + wv;
    int n = n0 < N ? n0 : N-1;

    if (ln < TV) vi_s[wv][ln] = vecs[(size_t)n*TV + ln];
    float R[9];
    #pragma unroll
    for (int i = 0; i < 9; i++) R[i] = frames[(size_t)n*9 + i];

    float pa[32];
    {
        const uint4* p4 = (const uint4*)(P + (size_t)n*1024 + c*32);
        #pragma unroll
        for (int q = 0; q < 4; q++) unpack8(p4[q], pa + 8*q);
    }
    int e0 = start[n], e1 = start[n+1];
    float a0 = 0.f, a1 = 0.f, a2 = 0.f;

    for (int t = e0 + sub; t < e1; t += 4){
        int row = elist[t];
        float l[32]; float s = 0.f;
        {
            const uint4* p4 = (const uint4*)(P + (size_t)row*1024 + 512 + c*32);
            #pragma unroll
            for (int q = 0; q < 4; q++){
                float tmp[8]; unpack8(p4[q], tmp);
                #pragma unroll
                for (int r = 0; r < 8; r++){
                    float x = pa[8*q+r] + tmp[r];
                    l[8*q+r] = x; s += x;
                }
            }
        }
        #pragma unroll
        for (int off = 1; off < 16; off <<= 1) s += __shfl_xor(s, off, 64);
        float mu = s * (1.0f/NK);
        float sq = 0.f;
        #pragma unroll
        for (int i = 0; i < 32; i++){ float d = l[i] - mu; l[i] = d; sq = fmaf(d, d, sq); }
        #pragma unroll
        for (int off = 1; off < 16; off <<= 1) sq += __shfl_xor(sq, off, 64);
        float inv = rsqrtf(sq*(1.0f/NK) + 1e-5f);

        float w[32];
        {
            const float4* g4 = (const float4*)(gi_t  + c*32);
            const float4* b4 = (const float4*)(bbi_t + c*32);
            #pragma unroll
            for (int q = 0; q < 8; q++){
                float4 gg = g4[q], bb = b4[q];
                float gx[4] = {gg.x, gg.y, gg.z, gg.w};
                float bx[4] = {bb.x, bb.y, bb.z, bb.w};
                #pragma unroll
                for (int r = 0; r < 4; r++){
                    float y = fmaf(gx[r], l[4*q+r]*inv, bx[r]);
                    w[4*q+r] = 1.0f / (1.0f + __expf(-y));
                }
            }
        }
        {   // vj_in_i for this edge's channel c: Ri^T @ gvec[row][c]
            const float* gr = gvec + (size_t)row*TV + c*3;
            float g0 = gr[0], g1 = gr[1], g2 = gr[2];
            #pragma unroll
            for (int i = 0; i < 3; i++)
                vj_s[wv][sub][c*3+i] = R[0+i]*g0 + R[3+i]*g1 + R[6+i]*g2;
        }
        #pragma unroll
        for (int kk = 0; kk < 16; kk++){
            float wl = w[kk], wh = w[16+kk];
            a0 = fmaf(vi_s[wv][kk*3+0], wl, a0);
            a1 = fmaf(vi_s[wv][kk*3+1], wl, a1);
            a2 = fmaf(vi_s[wv][kk*3+2], wl, a2);
            a0 = fmaf(vj_s[wv][sub][kk*3+0], wh, a0);
            a1 = fmaf(vj_s[wv][sub][kk*3+1], wh, a1);
            a2 = fmaf(vj_s[wv][sub][kk*3+2], wh, a2);
        }
    }
    a0 += __shfl_xor(a0,16,64); a0 += __shfl_xor(a0,32,64);
    a1 += __shfl_xor(a1,16,64); a1 += __shfl_xor(a1,32,64);
    a2 += __shfl_xor(a2,16,64); a2 += __shfl_xor(a2,32,64);
    if (ln < 16 && n0 < N){
        size_t o = (size_t)n*TV + c*3;
        out[o+0] = vprev[o+0] + a0;
        out[o+1] = vprev[o+1] + a1;
        out[o+2] = vprev[o+2] + a2;
    }
}

// ============================================================================
extern "C" void kernel_launch(void* const* d_in, const int* in_sizes, int n_in,
                              void* d_out, int out_size, void* d_ws, size_t ws_size,
                              hipStream_t stream){
    const float* h      = (const float*)d_in[1];
    const void*  eidx   = d_in[2];
    const float* frames = (const float*)d_in[3];
    const float* vprev  = (const float*)d_in[5];
    const float* W1  = (const float*)d_in[6];
    const float* b1  = (const float*)d_in[7];
    const float* g1  = (const float*)d_in[8];
    const float* bb1 = (const float*)d_in[9];
    const float* W2  = (const float*)d_in[10];
    const float* b2  = (const float*)d_in[11];
    const float* g2  = (const float*)d_in[12];
    const float* bb2 = (const float*)d_in[13];
    const float* Wi  = (const float*)d_in[14];
    const float* bi  = (const float*)d_in[15];
    const float* gi  = (const float*)d_in[16];
    const float* bbi = (const float*)d_in[17];
    float* out = (float*)d_out;

    const int N = in_sizes[1] / DD;
    const int E = in_sizes[2] / 2;
    const int Np = ((N + 63) / 64) * 64;

    // workspace carve-up
    float* ws     = (float*)d_ws;
    float* Wt     = ws;                         // 131072 f
    float* bias_t = Wt + 131072;                // 1024
    float* gi_t   = bias_t + 1024;              // 512
    float* bbi_t  = gi_t + 512;                 // 512
    float* vecs   = bbi_t + 512;                // N*48
    float* gvec   = vecs + (size_t)N*TV;        // N*48
    unsigned short* P = (unsigned short*)(gvec + (size_t)N*TV);  // Np*1024 bf16
    int*   idx32  = (int*)(P + (size_t)Np*1024);   // 2E
    int*   cnt    = idx32 + 2*(size_t)E;           // N
    int*   startp = cnt + N;                       // N+1
    int*   cursor = startp + N + 1;                // N
    int*   elist  = cursor + N;                    // E
    int*   dflag  = elist + E;                     // 1

    int nchk = E < 4096 ? E : 4096;
    detect_i64<<<1, 256, 0, stream>>>((const int*)eidx, nchk, dflag);
    zero_cnt<<<(N + 255)/256, 256, 0, stream>>>(cnt, N);
    cvt_hist<<<(2*E + 255)/256, 256, 0, stream>>>(eidx, idx32, cnt, 2*E, E, dflag);
    build_wt<<<1024, 128, 0, stream>>>(Wi, bi, gi, bbi, Wt, bias_t, gi_t, bbi_t);
    vinit<<<(N + 3)/4, 256, 0, stream>>>(h, W1, b1, g1, bb1, W2, b2, g2, bb2,
                                         frames, vecs, gvec, N);
    dim3 ggrid(1024/BN, Np/BM);
    gemm_p<<<ggrid, 256, 0, stream>>>(h, Wt, bias_t, P, N);
    scan_k<<<1, 1024, 0, stream>>>(cnt, startp, cursor, N);
    scatter_k<<<(E + 255)/256, 256, 0, stream>>>(idx32, cursor, elist, E);
    node_k<<<(N + 3)/4, 256, 0, stream>>>(P, vecs, gvec, frames, startp, elist,
                                          vprev, gi_t, bbi_t, out, N);
    (void)ws_size; (void)n_in; (void)out_size;
}